// Round 4
// baseline (184.313 us; speedup 1.0000x reference)
//
#include <hip/hip_runtime.h>
#include <cmath>

// Problem constants (from reference): N=2, Lq=Lk=1024, H=8, d=64, P=1, D=512
#define NB    2
#define LSEQ  1024
#define NH    8
#define HD    64
#define DD    512    // NH*HD
#define FDIM  128    // 2*HD  (cos|sin features)
#define EV    65     // HD + 1 (values + denominator unit column)
#define CHUNK 64
#define NC    16     // LSEQ / CHUNK
#define NBH   16     // NB*NH

typedef short short8 __attribute__((ext_vector_type(8)));   // 8 bf16 (4 VGPRs)
typedef float floatx4 __attribute__((ext_vector_type(4)));  // MFMA C/D frag

__device__ __forceinline__ float softplusf(float x) {
  // jax.nn.softplus == logaddexp(x, 0) == max(x,0) + log1p(exp(-|x|))
  return fmaxf(x, 0.0f) + log1pf(expf(-fabsf(x)));
}

__device__ __forceinline__ unsigned short f2bf(float f) {
  unsigned u = __float_as_uint(f);
  u += 0x7fffu + ((u >> 16) & 1u);
  return (unsigned short)(u >> 16);
}

__device__ __forceinline__ short8 cvt8(float4 a, float4 b) {
  short8 r;
  r[0] = (short)f2bf(a.x); r[1] = (short)f2bf(a.y);
  r[2] = (short)f2bf(a.z); r[3] = (short)f2bf(a.w);
  r[4] = (short)f2bf(b.x); r[5] = (short)f2bf(b.y);
  r[6] = (short)f2bf(b.z); r[7] = (short)f2bf(b.w);
  return r;
}

// ---------------------------------------------------------------------------
// K1: ALL projections in one launch (q blocks 0..255, k/v blocks 256..767)
// so the independent GEMMs overlap instead of serializing in the graph.
// bf16 MFMA 16x16x32, 64x64 tile, 4 waves; fp32 accumulate; fused epilogue.
// ---------------------------------------------------------------------------
__global__ __launch_bounds__(256) void k_proj(
    const float* __restrict__ Xq, const float* __restrict__ Xkv,
    const float* __restrict__ Wq, const float* __restrict__ Wk,
    const float* __restrict__ Wv, const float* __restrict__ pw,
    const float* __restrict__ pb, const float* __restrict__ pc,
    float* __restrict__ Qf, float* __restrict__ Kf, float* __restrict__ Vx)
{
  __shared__ short Al[64][32];   // [m][k] bf16, 4 KB
  __shared__ short Bl[64][32];   // [e][k] bf16, 4 KB
  const int b = blockIdx.x;
  int m0, e0, pmode;             // 0 = q, 1 = k, 2 = v
  const float *X, *W;
  if (b < 256) {
    m0 = (b >> 3) << 6; e0 = (b & 7) << 6;
    X = Xq; W = Wq + (size_t)e0 * DD; pmode = 0;
  } else {
    const int bb = b - 256;
    m0 = (bb >> 4) << 6;
    const int nt = bb & 15;
    e0 = (nt & 7) << 6;
    X = Xkv;
    if (nt < 8) { W = Wk + (size_t)e0 * DD; pmode = 1; }
    else        { W = Wv + (size_t)e0 * DD; pmode = 2; }
  }
  const int tid  = threadIdx.x;
  const int r    = tid >> 2;               // staging row 0..63
  const int ko   = (tid & 3) << 3;         // staging k-offset 0,8,16,24
  const int wave = tid >> 6, lane = tid & 63;
  const int quad = lane >> 4, lm = lane & 15;
  const float* Ag = X + (size_t)(m0 + r) * DD + ko;
  const float* Bg = W + (size_t)r * DD + ko;
  floatx4 acc[4] = {};
  for (int k0 = 0; k0 < DD; k0 += 32) {
    const float4 a0 = *(const float4*)(Ag + k0);
    const float4 a1 = *(const float4*)(Ag + k0 + 4);
    const float4 b0 = *(const float4*)(Bg + k0);
    const float4 b1 = *(const float4*)(Bg + k0 + 4);
    __syncthreads();
    *(short8*)&Al[r][ko] = cvt8(a0, a1);
    *(short8*)&Bl[r][ko] = cvt8(b0, b1);
    __syncthreads();
    const short8 af = *(const short8*)&Al[(wave << 4) + lm][quad << 3];
#pragma unroll
    for (int t = 0; t < 4; ++t) {
      const short8 bf = *(const short8*)&Bl[(t << 4) + lm][quad << 3];
      acc[t] = __builtin_amdgcn_mfma_f32_16x16x32_bf16(af, bf, acc[t], 0, 0, 0);
    }
  }
#pragma unroll
  for (int t = 0; t < 4; ++t) {
    const int e = e0 + (t << 4) + lm;      // global e in [0,512)
    const int h = e >> 6, jj = e & 63;
    if (pmode == 2) {
#pragma unroll
      for (int rg = 0; rg < 4; ++rg) {
        const int m = m0 + (wave << 4) + (quad << 2) + rg;
        const int n = m >> 10, l = m & 1023;
        Vx[((size_t)(n * NH + h) * LSEQ + l) * HD + jj] = acc[t][rg];
      }
    } else {
      const float pwv = pw[e];
      const float pbv = (pmode == 0) ? pb[e] : 0.0f;
      const float pcv = (pmode == 0) ? pc[e] : 1.0f;
      float* base = (pmode == 0) ? Qf : Kf;
#pragma unroll
      for (int rg = 0; rg < 4; ++rg) {
        const int m = m0 + (wave << 4) + (quad << 2) + rg;
        const int n = m >> 10, l = m & 1023;
        const float v = softplusf(acc[t][rg]) * pcv;
        const float ang = fmaf((float)l, pwv, pbv);
        const float sn = __sinf(ang), cs = __cosf(ang);
        float* dst = &base[((size_t)(n * NH + h) * LSEQ + l) * FDIM + jj];
        dst[0]  = v * cs;
        dst[64] = v * sn;
      }
    }
  }
}

// ---------------------------------------------------------------------------
// K2: per-chunk state sums. S[bh*NC+c][f][e] = sum_{t in chunk} Kf[t][f]*Vext[t][e]
// where Vext[:,64] = 1 (denominator column).
// ---------------------------------------------------------------------------
__global__ __launch_bounds__(256) void k_chunk_sums(
    const float* __restrict__ Kf, const float* __restrict__ Vx,
    float* __restrict__ S)
{
  const int c  = blockIdx.x & (NC - 1);
  const int bh = blockIdx.x >> 4;
  const int t0 = c * CHUNK;
  const int tid = threadIdx.x;
  __shared__ float Ks[CHUNK][FDIM];  // 32 KB
  __shared__ float Vs[CHUNK][HD];    // 16 KB
  for (int i = tid; i < CHUNK * (FDIM / 4); i += 256) {
    const int r = i >> 5, c4 = (i & 31) << 2;
    *(float4*)&Ks[r][c4] = *(const float4*)&Kf[((size_t)bh * LSEQ + t0 + r) * FDIM + c4];
  }
  for (int i = tid; i < CHUNK * (HD / 4); i += 256) {
    const int r = i >> 4, c4 = (i & 15) << 2;
    *(float4*)&Vs[r][c4] = *(const float4*)&Vx[((size_t)bh * LSEQ + t0 + r) * HD + c4];
  }
  __syncthreads();
  float* Sb = &S[(size_t)blockIdx.x * FDIM * EV];
  for (int task = tid; task < 32 * 17; task += 256) {
    const int ft = task & 31;          // f-tile (4 wide)
    const int et = task >> 5;          // e-tile (4 wide), et==16 -> unit column
    const int f0 = ft << 2;
    if (et == 16) {
      float s[4] = {};
      for (int t = 0; t < CHUNK; ++t) {
        const float4 k4 = *(const float4*)&Ks[t][f0];
        s[0] += k4.x; s[1] += k4.y; s[2] += k4.z; s[3] += k4.w;
      }
#pragma unroll
      for (int u = 0; u < 4; ++u) Sb[(f0 + u) * EV + 64] = s[u];
    } else {
      const int e0 = et << 2;
      float a[4][4] = {};
      for (int t = 0; t < CHUNK; ++t) {
        const float4 k4 = *(const float4*)&Ks[t][f0];
        const float4 v4 = *(const float4*)&Vs[t][e0];
        const float kv[4] = {k4.x, k4.y, k4.z, k4.w};
        const float vv[4] = {v4.x, v4.y, v4.z, v4.w};
#pragma unroll
        for (int i = 0; i < 4; ++i)
#pragma unroll
          for (int j = 0; j < 4; ++j)
            a[i][j] = fmaf(kv[i], vv[j], a[i][j]);
      }
#pragma unroll
      for (int i = 0; i < 4; ++i)
#pragma unroll
        for (int j = 0; j < 4; ++j)
          Sb[(f0 + i) * EV + e0 + j] = a[i][j];
    }
  }
}

// ---------------------------------------------------------------------------
// K3: in-place exclusive prefix scan over the NC chunk states per bh.
// 256 blocks (16 bh x 16 groups of 8 f-rows) so all CUs participate.
// ---------------------------------------------------------------------------
__global__ __launch_bounds__(256) void k_scan(float* __restrict__ S)
{
  const int bh = blockIdx.x >> 4;
  const int fg = blockIdx.x & 15;          // f-group of 8 rows
  float* Sb = S + (size_t)bh * NC * FDIM * EV + (size_t)fg * 8 * EV;
  const size_t cs = (size_t)FDIM * EV;     // chunk stride
  for (int i = threadIdx.x; i < 8 * EV; i += 256) {
    float* p = Sb + i;
    float v[NC];
#pragma unroll
    for (int c = 0; c < NC; ++c) v[c] = p[c * cs];
    float s = 0.0f;
#pragma unroll
    for (int c = 0; c < NC; ++c) { const float t = v[c]; p[c * cs] = s; s += t; }
  }
}

// ---------------------------------------------------------------------------
// K4: per-chunk output, fused single-pass version.
// 1024 threads: thread = (row m = tid>>4, 4-col group tx = tid&15).
// One f-loop computes QK^T scores, Q@P numerator AND the Q@P[:,64]
// denominator part (identical across tx -> no reduction). The Sc@V t-loop
// folds in the Sc row-sum part of the denominator. Q is read exactly once.
// ---------------------------------------------------------------------------
__global__ __launch_bounds__(1024) void k_chunk_out(
    const float* __restrict__ Qf, const float* __restrict__ Kf,
    const float* __restrict__ Vx, const float* __restrict__ S,
    float* __restrict__ Out)
{
  const int c  = blockIdx.x & (NC - 1);
  const int bh = blockIdx.x >> 4;
  const int n  = bh >> 3;
  const int h  = bh & 7;
  const int t0 = c * CHUNK;
  const int tid = threadIdx.x;
  const int m  = tid >> 4;           // row 0..63
  const int tx = tid & 15;           // 4-wide e / t group

  __shared__ float P[FDIM][68];      // 34816 B (pad keeps float4 rows aligned)
  __shared__ float Sc[CHUNK][68];    // 17408 B

  // load prefix state (coalesced)
  {
    const float* Pg = &S[(size_t)(bh * NC + c) * FDIM * EV];
    for (int i = tid; i < FDIM * EV; i += 1024) {
      const int f = i / EV;
      const int e = i - f * EV;
      P[f][e] = Pg[i];
    }
  }
  __syncthreads();

  const float* Qrow = &Qf[((size_t)bh * LSEQ + t0 + m) * FDIM];
  const float* Kb   = &Kf[((size_t)bh * LSEQ + t0) * FDIM];
  float accS[4] = {};   // scores vs t = 4tx..4tx+3
  float o[4]    = {};   // numerator cols e = 4tx..4tx+3
  float den     = 0.0f;
  for (int f = 0; f < FDIM; f += 4) {
    const float4 q4 = *(const float4*)&Qrow[f];
    const float qr[4] = {q4.x, q4.y, q4.z, q4.w};
    float kk[4][4];
#pragma unroll
    for (int j = 0; j < 4; ++j) {
      const float4 k4 = *(const float4*)&Kb[((tx << 2) + j) * FDIM + f];
      kk[j][0] = k4.x; kk[j][1] = k4.y; kk[j][2] = k4.z; kk[j][3] = k4.w;
    }
#pragma unroll
    for (int u = 0; u < 4; ++u) {
      const float4 p4 = *(const float4*)&P[f + u][tx << 2];
      accS[0] = fmaf(qr[u], kk[0][u], accS[0]);
      accS[1] = fmaf(qr[u], kk[1][u], accS[1]);
      accS[2] = fmaf(qr[u], kk[2][u], accS[2]);
      accS[3] = fmaf(qr[u], kk[3][u], accS[3]);
      o[0] = fmaf(qr[u], p4.x, o[0]);
      o[1] = fmaf(qr[u], p4.y, o[1]);
      o[2] = fmaf(qr[u], p4.z, o[2]);
      o[3] = fmaf(qr[u], p4.w, o[3]);
      den  = fmaf(qr[u], P[f + u][64], den);
    }
  }
#pragma unroll
  for (int j = 0; j < 4; ++j) {
    const int t = (tx << 2) + j;
    Sc[m][t] = (t <= m) ? accS[j] : 0.0f;
  }
  __syncthreads();

  const float* Vb = &Vx[((size_t)bh * LSEQ + t0) * HD];
  for (int t = 0; t < CHUNK; ++t) {
    const float sm = Sc[m][t];
    const float4 v4 = *(const float4*)&Vb[t * HD + (tx << 2)];
    o[0] = fmaf(sm, v4.x, o[0]);
    o[1] = fmaf(sm, v4.y, o[1]);
    o[2] = fmaf(sm, v4.z, o[2]);
    o[3] = fmaf(sm, v4.w, o[3]);
    den += sm;          // Sc row-sum; identical across the 16 tx lanes
  }
  const float r = 1.0f / den;
  float4 res;
  res.x = o[0] * r; res.y = o[1] * r; res.z = o[2] * r; res.w = o[3] * r;
  *(float4*)&Out[((size_t)(n * LSEQ + t0 + m)) * DD + h * HD + (tx << 2)] = res;
}

// ---------------------------------------------------------------------------
extern "C" void kernel_launch(void* const* d_in, const int* in_sizes, int n_in,
                              void* d_out, int out_size, void* d_ws, size_t ws_size,
                              hipStream_t stream) {
  (void)in_sizes; (void)n_in; (void)out_size; (void)ws_size;
  const float* query  = (const float*)d_in[0];
  const float* keyseq = (const float*)d_in[1];
  const float* Wq     = (const float*)d_in[2];
  const float* Wk     = (const float*)d_in[3];
  const float* Wv     = (const float*)d_in[4];
  const float* pc     = (const float*)d_in[5];  // position_coeffs (H,d)
  const float* pw     = (const float*)d_in[6];  // position_weight (H,d,1)
  const float* pb     = (const float*)d_in[7];  // position_bias (H,d)
  float* out = (float*)d_out;

  float* ws = (float*)d_ws;
  float* Qf = ws;                                   // 16*1024*128 floats
  float* Kf = Qf + (size_t)NBH * LSEQ * FDIM;
  float* Vx = Kf + (size_t)NBH * LSEQ * FDIM;
  float* S  = Vx + (size_t)NBH * LSEQ * HD;         // 16*16*128*65 floats
  // total ws: 29.5 MB

  k_proj      <<<768,      256,  0, stream>>>(query, keyseq, Wq, Wk, Wv, pw, pb, pc, Qf, Kf, Vx);
  k_chunk_sums<<<NBH * NC, 256,  0, stream>>>(Kf, Vx, S);
  k_scan      <<<NBH * NC, 256,  0, stream>>>(S);
  k_chunk_out <<<NBH * NC, 1024, 0, stream>>>(Qf, Kf, Vx, S, out);
}

// Round 5
// 132.106 us; speedup vs baseline: 1.3952x; 1.3952x over previous
//
#include <hip/hip_runtime.h>
#include <cmath>

// Problem constants (from reference): N=2, Lq=Lk=1024, H=8, d=64, P=1, D=512
#define NB    2
#define LSEQ  1024
#define NH    8
#define HD    64
#define DD    512    // NH*HD
#define FDIM  128    // 2*HD  (cos|sin features)
#define EV    65     // HD + 1 (values + denominator unit column)
#define CHUNK 64
#define NC    16     // LSEQ / CHUNK
#define NBH   16     // NB*NH

typedef short short8 __attribute__((ext_vector_type(8)));   // 8 bf16 (4 VGPRs)
typedef float floatx4 __attribute__((ext_vector_type(4)));  // MFMA C/D frag

__device__ __forceinline__ float softplusf(float x) {
  return fmaxf(x, 0.0f) + log1pf(expf(-fabsf(x)));
}

__device__ __forceinline__ unsigned short f2bf(float f) {
  unsigned u = __float_as_uint(f);
  u += 0x7fffu + ((u >> 16) & 1u);
  return (unsigned short)(u >> 16);
}

__device__ __forceinline__ short8 cvt8(float4 a, float4 b) {
  short8 r;
  r[0] = (short)f2bf(a.x); r[1] = (short)f2bf(a.y);
  r[2] = (short)f2bf(a.z); r[3] = (short)f2bf(a.w);
  r[4] = (short)f2bf(b.x); r[5] = (short)f2bf(b.y);
  r[6] = (short)f2bf(b.z); r[7] = (short)f2bf(b.w);
  return r;
}

// ---------------------------------------------------------------------------
// K1: ALL projections in one launch (q blocks 0..255, k/v blocks 256..767).
// bf16 MFMA 16x16x32, 64x64 tile, 4 waves; fp32 accumulate; fused epilogue.
// ---------------------------------------------------------------------------
__global__ __launch_bounds__(256) void k_proj(
    const float* __restrict__ Xq, const float* __restrict__ Xkv,
    const float* __restrict__ Wq, const float* __restrict__ Wk,
    const float* __restrict__ Wv, const float* __restrict__ pw,
    const float* __restrict__ pb, const float* __restrict__ pc,
    float* __restrict__ Qf, float* __restrict__ Kf, float* __restrict__ Vx)
{
  __shared__ short Al[64][32];   // [m][k] bf16, 4 KB
  __shared__ short Bl[64][32];   // [e][k] bf16, 4 KB
  const int b = blockIdx.x;
  int m0, e0, pmode;             // 0 = q, 1 = k, 2 = v
  const float *X, *W;
  if (b < 256) {
    m0 = (b >> 3) << 6; e0 = (b & 7) << 6;
    X = Xq; W = Wq + (size_t)e0 * DD; pmode = 0;
  } else {
    const int bb = b - 256;
    m0 = (bb >> 4) << 6;
    const int nt = bb & 15;
    e0 = (nt & 7) << 6;
    X = Xkv;
    if (nt < 8) { W = Wk + (size_t)e0 * DD; pmode = 1; }
    else        { W = Wv + (size_t)e0 * DD; pmode = 2; }
  }
  const int tid  = threadIdx.x;
  const int r    = tid >> 2;
  const int ko   = (tid & 3) << 3;
  const int wave = tid >> 6, lane = tid & 63;
  const int quad = lane >> 4, lm = lane & 15;
  const float* Ag = X + (size_t)(m0 + r) * DD + ko;
  const float* Bg = W + (size_t)r * DD + ko;
  floatx4 acc[4] = {};
  for (int k0 = 0; k0 < DD; k0 += 32) {
    const float4 a0 = *(const float4*)(Ag + k0);
    const float4 a1 = *(const float4*)(Ag + k0 + 4);
    const float4 b0 = *(const float4*)(Bg + k0);
    const float4 b1 = *(const float4*)(Bg + k0 + 4);
    __syncthreads();
    *(short8*)&Al[r][ko] = cvt8(a0, a1);
    *(short8*)&Bl[r][ko] = cvt8(b0, b1);
    __syncthreads();
    const short8 af = *(const short8*)&Al[(wave << 4) + lm][quad << 3];
#pragma unroll
    for (int t = 0; t < 4; ++t) {
      const short8 bf = *(const short8*)&Bl[(t << 4) + lm][quad << 3];
      acc[t] = __builtin_amdgcn_mfma_f32_16x16x32_bf16(af, bf, acc[t], 0, 0, 0);
    }
  }
#pragma unroll
  for (int t = 0; t < 4; ++t) {
    const int e = e0 + (t << 4) + lm;
    const int h = e >> 6, jj = e & 63;
    if (pmode == 2) {
#pragma unroll
      for (int rg = 0; rg < 4; ++rg) {
        const int m = m0 + (wave << 4) + (quad << 2) + rg;
        const int n = m >> 10, l = m & 1023;
        Vx[((size_t)(n * NH + h) * LSEQ + l) * HD + jj] = acc[t][rg];
      }
    } else {
      const float pwv = pw[e];
      const float pbv = (pmode == 0) ? pb[e] : 0.0f;
      const float pcv = (pmode == 0) ? pc[e] : 1.0f;
      float* base = (pmode == 0) ? Qf : Kf;
#pragma unroll
      for (int rg = 0; rg < 4; ++rg) {
        const int m = m0 + (wave << 4) + (quad << 2) + rg;
        const int n = m >> 10, l = m & 1023;
        const float v = softplusf(acc[t][rg]) * pcv;
        const float ang = fmaf((float)l, pwv, pbv);
        const float sn = __sinf(ang), cs = __cosf(ang);
        float* dst = &base[((size_t)(n * NH + h) * LSEQ + l) * FDIM + jj];
        dst[0]  = v * cs;
        dst[64] = v * sn;
      }
    }
  }
}

// ---------------------------------------------------------------------------
// K2: per-chunk state sums. S[bh*NC+c][f][e] = sum_t Kf[t][f]*Vext[t][e]
// ---------------------------------------------------------------------------
__global__ __launch_bounds__(256) void k_chunk_sums(
    const float* __restrict__ Kf, const float* __restrict__ Vx,
    float* __restrict__ S)
{
  const int c  = blockIdx.x & (NC - 1);
  const int bh = blockIdx.x >> 4;
  const int t0 = c * CHUNK;
  const int tid = threadIdx.x;
  __shared__ float Ks[CHUNK][FDIM];  // 32 KB
  __shared__ float Vs[CHUNK][HD];    // 16 KB
  for (int i = tid; i < CHUNK * (FDIM / 4); i += 256) {
    const int r = i >> 5, c4 = (i & 31) << 2;
    *(float4*)&Ks[r][c4] = *(const float4*)&Kf[((size_t)bh * LSEQ + t0 + r) * FDIM + c4];
  }
  for (int i = tid; i < CHUNK * (HD / 4); i += 256) {
    const int r = i >> 4, c4 = (i & 15) << 2;
    *(float4*)&Vs[r][c4] = *(const float4*)&Vx[((size_t)bh * LSEQ + t0 + r) * HD + c4];
  }
  __syncthreads();
  float* Sb = &S[(size_t)blockIdx.x * FDIM * EV];
  for (int task = tid; task < 32 * 17; task += 256) {
    const int ft = task & 31;
    const int et = task >> 5;
    const int f0 = ft << 2;
    if (et == 16) {
      float s[4] = {};
      for (int t = 0; t < CHUNK; ++t) {
        const float4 k4 = *(const float4*)&Ks[t][f0];
        s[0] += k4.x; s[1] += k4.y; s[2] += k4.z; s[3] += k4.w;
      }
#pragma unroll
      for (int u = 0; u < 4; ++u) Sb[(f0 + u) * EV + 64] = s[u];
    } else {
      const int e0 = et << 2;
      float a[4][4] = {};
      for (int t = 0; t < CHUNK; ++t) {
        const float4 k4 = *(const float4*)&Ks[t][f0];
        const float4 v4 = *(const float4*)&Vs[t][e0];
        const float kv[4] = {k4.x, k4.y, k4.z, k4.w};
        const float vv[4] = {v4.x, v4.y, v4.z, v4.w};
#pragma unroll
        for (int i = 0; i < 4; ++i)
#pragma unroll
          for (int j = 0; j < 4; ++j)
            a[i][j] = fmaf(kv[i], vv[j], a[i][j]);
      }
#pragma unroll
      for (int i = 0; i < 4; ++i)
#pragma unroll
        for (int j = 0; j < 4; ++j)
          Sb[(f0 + i) * EV + e0 + j] = a[i][j];
    }
  }
}

// ---------------------------------------------------------------------------
// K3: in-place exclusive prefix scan over the NC chunk states per bh.
// ---------------------------------------------------------------------------
__global__ __launch_bounds__(256) void k_scan(float* __restrict__ S)
{
  const int bh = blockIdx.x >> 4;
  const int fg = blockIdx.x & 15;          // f-group of 8 rows
  float* Sb = S + (size_t)bh * NC * FDIM * EV + (size_t)fg * 8 * EV;
  const size_t cs = (size_t)FDIM * EV;
  for (int i = threadIdx.x; i < 8 * EV; i += 256) {
    float* p = Sb + i;
    float v[NC];
#pragma unroll
    for (int c = 0; c < NC; ++c) v[c] = p[c * cs];
    float s = 0.0f;
#pragma unroll
    for (int c = 0; c < NC; ++c) { const float t = v[c]; p[c * cs] = s; s += t; }
  }
}

// ---------------------------------------------------------------------------
// K4 v3: per-(chunk, half) output block. 512 blocks x 256 threads.
// LDS-staged: Qs (this half's 32 Q rows), U = K^T then (after barrier) the
// prefix state P, Sc = masked scores. V streamed via L1 (256 KB/block).
// Thread = 2 rows x 4 cols. Denominator fused (no extra pass, no reduction).
// ---------------------------------------------------------------------------
__global__ __launch_bounds__(256) void k_chunk_out(
    const float* __restrict__ Qf, const float* __restrict__ Kf,
    const float* __restrict__ Vx, const float* __restrict__ S,
    float* __restrict__ Out)
{
  const int blk  = blockIdx.x;
  const int bh   = blk >> 5;
  const int c    = (blk >> 1) & (NC - 1);
  const int half = blk & 1;
  const int n    = bh >> 3, h = bh & 7;
  const int t0   = c * CHUNK;
  const int r0   = half << 5;            // 0 or 32: this block's row offset
  const int tid  = threadIdx.x;
  const int ty   = tid >> 4, tx = tid & 15;
  const int lm0  = ty << 1;              // local rows lm0, lm0+1 (0..31)

  __shared__ float U[FDIM][68];          // 34816 B: K^T, then P
  __shared__ float Qs[32][132];          // 16896 B (pad 4 -> rows hit distinct banks)
  __shared__ float Sc[32][68];           //  8704 B           total 60416 B

  // stage Q rows r0..r0+31
  for (int i = tid; i < 32 * 32; i += 256) {
    const int row = i >> 5, c4 = (i & 31) << 2;
    *(float4*)&Qs[row][c4] =
        *(const float4*)&Qf[((size_t)bh * LSEQ + t0 + r0 + row) * FDIM + c4];
  }
  // stage K transposed: U[f][t] = Kf[t0+t][f]  (t = lane -> conflict-free writes)
  for (int i = tid; i < 64 * 32; i += 256) {
    const int t = i & 63, f4 = (i >> 6) << 2;
    const float4 k4 = *(const float4*)&Kf[((size_t)bh * LSEQ + t0 + t) * FDIM + f4];
    U[f4 + 0][t] = k4.x; U[f4 + 1][t] = k4.y;
    U[f4 + 2][t] = k4.z; U[f4 + 3][t] = k4.w;
  }
  __syncthreads();

  // score phase: accS[i][j] = sum_f Q[r0+lm0+i][f] * K[4tx+j][f]
  float accS[2][4] = {};
  for (int f = 0; f < FDIM; f += 4) {
    const float4 q0 = *(const float4*)&Qs[lm0][f];
    const float4 q1 = *(const float4*)&Qs[lm0 + 1][f];
    const float qa[2][4] = {{q0.x, q0.y, q0.z, q0.w}, {q1.x, q1.y, q1.z, q1.w}};
#pragma unroll
    for (int u = 0; u < 4; ++u) {
      const float4 k4 = *(const float4*)&U[f + u][tx << 2];
      const float kv[4] = {k4.x, k4.y, k4.z, k4.w};
#pragma unroll
      for (int i = 0; i < 2; ++i)
#pragma unroll
        for (int j = 0; j < 4; ++j)
          accS[i][j] = fmaf(qa[i][u], kv[j], accS[i][j]);
    }
  }
  // causal mask (global row = r0+lm, col = t) and store
#pragma unroll
  for (int i = 0; i < 2; ++i) {
    const int m = r0 + lm0 + i;
#pragma unroll
    for (int j = 0; j < 4; ++j) {
      const int t = (tx << 2) + j;
      Sc[lm0 + i][t] = (t <= m) ? accS[i][j] : 0.0f;
    }
  }
  __syncthreads();   // everyone done reading U as K^T

  // re-stage U as the prefix state P
  {
    const float* Pg = &S[(size_t)(bh * NC + c) * FDIM * EV];
    for (int i = tid; i < FDIM * EV; i += 256) {
      const int f = i / EV;
      const int e = i - f * EV;
      U[f][e] = Pg[i];
    }
  }
  __syncthreads();

  // numerator Q@P + fused denominator part (den col e=64, broadcast read)
  float o[2][4] = {};
  float den[2]  = {};
  for (int f = 0; f < FDIM; f += 4) {
    const float4 q0 = *(const float4*)&Qs[lm0][f];
    const float4 q1 = *(const float4*)&Qs[lm0 + 1][f];
    const float qa[2][4] = {{q0.x, q0.y, q0.z, q0.w}, {q1.x, q1.y, q1.z, q1.w}};
#pragma unroll
    for (int u = 0; u < 4; ++u) {
      const float4 p4 = *(const float4*)&U[f + u][tx << 2];
      const float pv[4] = {p4.x, p4.y, p4.z, p4.w};
      const float pd = U[f + u][64];
#pragma unroll
      for (int i = 0; i < 2; ++i) {
#pragma unroll
        for (int j = 0; j < 4; ++j)
          o[i][j] = fmaf(qa[i][u], pv[j], o[i][j]);
        den[i] = fmaf(qa[i][u], pd, den[i]);
      }
    }
  }

  // Sc@V + Sc row-sum into den (V streamed; per-block L1 traffic ~256 KB)
  const float* Vb = &Vx[((size_t)bh * LSEQ + t0) * HD];
  const int tmax = r0 + 32;              // rows in this half never see t >= r0+32
  for (int t = 0; t < tmax; ++t) {
    const float sm0 = Sc[lm0][t];
    const float sm1 = Sc[lm0 + 1][t];
    const float4 v4 = *(const float4*)&Vb[t * HD + (tx << 2)];
    o[0][0] = fmaf(sm0, v4.x, o[0][0]); o[0][1] = fmaf(sm0, v4.y, o[0][1]);
    o[0][2] = fmaf(sm0, v4.z, o[0][2]); o[0][3] = fmaf(sm0, v4.w, o[0][3]);
    o[1][0] = fmaf(sm1, v4.x, o[1][0]); o[1][1] = fmaf(sm1, v4.y, o[1][1]);
    o[1][2] = fmaf(sm1, v4.z, o[1][2]); o[1][3] = fmaf(sm1, v4.w, o[1][3]);
    den[0] += sm0;  den[1] += sm1;       // identical across tx lanes
  }

#pragma unroll
  for (int i = 0; i < 2; ++i) {
    const int l = t0 + r0 + lm0 + i;
    const float r = 1.0f / den[i];
    float4 res;
    res.x = o[i][0] * r; res.y = o[i][1] * r;
    res.z = o[i][2] * r; res.w = o[i][3] * r;
    *(float4*)&Out[((size_t)(n * LSEQ + l)) * DD + h * HD + (tx << 2)] = res;
  }
}

// ---------------------------------------------------------------------------
extern "C" void kernel_launch(void* const* d_in, const int* in_sizes, int n_in,
                              void* d_out, int out_size, void* d_ws, size_t ws_size,
                              hipStream_t stream) {
  (void)in_sizes; (void)n_in; (void)out_size; (void)ws_size;
  const float* query  = (const float*)d_in[0];
  const float* keyseq = (const float*)d_in[1];
  const float* Wq     = (const float*)d_in[2];
  const float* Wk     = (const float*)d_in[3];
  const float* Wv     = (const float*)d_in[4];
  const float* pc     = (const float*)d_in[5];  // position_coeffs (H,d)
  const float* pw     = (const float*)d_in[6];  // position_weight (H,d,1)
  const float* pb     = (const float*)d_in[7];  // position_bias (H,d)
  float* out = (float*)d_out;

  float* ws = (float*)d_ws;
  float* Qf = ws;
  float* Kf = Qf + (size_t)NBH * LSEQ * FDIM;
  float* Vx = Kf + (size_t)NBH * LSEQ * FDIM;
  float* S  = Vx + (size_t)NBH * LSEQ * HD;
  // total ws: 29.5 MB

  k_proj      <<<768,          256, 0, stream>>>(query, keyseq, Wq, Wk, Wv, pw, pb, pc, Qf, Kf, Vx);
  k_chunk_sums<<<NBH * NC,     256, 0, stream>>>(Kf, Vx, S);
  k_scan      <<<NBH * NC,     256, 0, stream>>>(S);
  k_chunk_out <<<NBH * NC * 2, 256, 0, stream>>>(Qf, Kf, Vx, S, out);
}

// Round 6
// 121.929 us; speedup vs baseline: 1.5116x; 1.0835x over previous
//
#include <hip/hip_runtime.h>
#include <cmath>

// Problem constants (from reference): N=2, Lq=Lk=1024, H=8, d=64, P=1, D=512
#define NB    2
#define LSEQ  1024
#define NH    8
#define HD    64
#define DD    512    // NH*HD
#define FDIM  128    // 2*HD  (cos|sin features)
#define EV    65     // HD + 1 (values + denominator unit column)
#define CHUNK 64
#define NC    16     // LSEQ / CHUNK
#define NBH   16     // NB*NH

typedef short short8 __attribute__((ext_vector_type(8)));   // 8 bf16 (4 VGPRs)
typedef float floatx4 __attribute__((ext_vector_type(4)));  // MFMA C/D frag

__device__ __forceinline__ float softplusf(float x) {
  return fmaxf(x, 0.0f) + log1pf(expf(-fabsf(x)));
}

__device__ __forceinline__ unsigned short f2bf(float f) {
  unsigned u = __float_as_uint(f);
  u += 0x7fffu + ((u >> 16) & 1u);
  return (unsigned short)(u >> 16);
}

__device__ __forceinline__ short8 cvt8(float4 a, float4 b) {
  short8 r;
  r[0] = (short)f2bf(a.x); r[1] = (short)f2bf(a.y);
  r[2] = (short)f2bf(a.z); r[3] = (short)f2bf(a.w);
  r[4] = (short)f2bf(b.x); r[5] = (short)f2bf(b.y);
  r[6] = (short)f2bf(b.z); r[7] = (short)f2bf(b.w);
  return r;
}

// ---------------------------------------------------------------------------
// K1: ALL projections in one launch (q blocks 0..255, k/v blocks 256..767).
// bf16 MFMA 16x16x32, 64x64 tile, 4 waves; fp32 accumulate; fused epilogue.
// ---------------------------------------------------------------------------
__global__ __launch_bounds__(256) void k_proj(
    const float* __restrict__ Xq, const float* __restrict__ Xkv,
    const float* __restrict__ Wq, const float* __restrict__ Wk,
    const float* __restrict__ Wv, const float* __restrict__ pw,
    const float* __restrict__ pb, const float* __restrict__ pc,
    float* __restrict__ Qf, float* __restrict__ Kf, float* __restrict__ Vx)
{
  __shared__ short Al[64][32];   // [m][k] bf16, 4 KB
  __shared__ short Bl[64][32];   // [e][k] bf16, 4 KB
  const int b = blockIdx.x;
  int m0, e0, pmode;             // 0 = q, 1 = k, 2 = v
  const float *X, *W;
  if (b < 256) {
    m0 = (b >> 3) << 6; e0 = (b & 7) << 6;
    X = Xq; W = Wq + (size_t)e0 * DD; pmode = 0;
  } else {
    const int bb = b - 256;
    m0 = (bb >> 4) << 6;
    const int nt = bb & 15;
    e0 = (nt & 7) << 6;
    X = Xkv;
    if (nt < 8) { W = Wk + (size_t)e0 * DD; pmode = 1; }
    else        { W = Wv + (size_t)e0 * DD; pmode = 2; }
  }
  const int tid  = threadIdx.x;
  const int r    = tid >> 2;
  const int ko   = (tid & 3) << 3;
  const int wave = tid >> 6, lane = tid & 63;
  const int quad = lane >> 4, lm = lane & 15;
  const float* Ag = X + (size_t)(m0 + r) * DD + ko;
  const float* Bg = W + (size_t)r * DD + ko;
  floatx4 acc[4] = {};
  for (int k0 = 0; k0 < DD; k0 += 32) {
    const float4 a0 = *(const float4*)(Ag + k0);
    const float4 a1 = *(const float4*)(Ag + k0 + 4);
    const float4 b0 = *(const float4*)(Bg + k0);
    const float4 b1 = *(const float4*)(Bg + k0 + 4);
    __syncthreads();
    *(short8*)&Al[r][ko] = cvt8(a0, a1);
    *(short8*)&Bl[r][ko] = cvt8(b0, b1);
    __syncthreads();
    const short8 af = *(const short8*)&Al[(wave << 4) + lm][quad << 3];
#pragma unroll
    for (int t = 0; t < 4; ++t) {
      const short8 bf = *(const short8*)&Bl[(t << 4) + lm][quad << 3];
      acc[t] = __builtin_amdgcn_mfma_f32_16x16x32_bf16(af, bf, acc[t], 0, 0, 0);
    }
  }
#pragma unroll
  for (int t = 0; t < 4; ++t) {
    const int e = e0 + (t << 4) + lm;
    const int h = e >> 6, jj = e & 63;
    if (pmode == 2) {
#pragma unroll
      for (int rg = 0; rg < 4; ++rg) {
        const int m = m0 + (wave << 4) + (quad << 2) + rg;
        const int n = m >> 10, l = m & 1023;
        Vx[((size_t)(n * NH + h) * LSEQ + l) * HD + jj] = acc[t][rg];
      }
    } else {
      const float pwv = pw[e];
      const float pbv = (pmode == 0) ? pb[e] : 0.0f;
      const float pcv = (pmode == 0) ? pc[e] : 1.0f;
      float* base = (pmode == 0) ? Qf : Kf;
#pragma unroll
      for (int rg = 0; rg < 4; ++rg) {
        const int m = m0 + (wave << 4) + (quad << 2) + rg;
        const int n = m >> 10, l = m & 1023;
        const float v = softplusf(acc[t][rg]) * pcv;
        const float ang = fmaf((float)l, pwv, pbv);
        const float sn = __sinf(ang), cs = __cosf(ang);
        float* dst = &base[((size_t)(n * NH + h) * LSEQ + l) * FDIM + jj];
        dst[0]  = v * cs;
        dst[64] = v * sn;
      }
    }
  }
}

// ---------------------------------------------------------------------------
// K2: per-chunk state sums. S[bh*NC+c][f][e] = sum_t Kf[t][f]*Vext[t][e]
// ---------------------------------------------------------------------------
__global__ __launch_bounds__(256) void k_chunk_sums(
    const float* __restrict__ Kf, const float* __restrict__ Vx,
    float* __restrict__ S)
{
  const int c  = blockIdx.x & (NC - 1);
  const int bh = blockIdx.x >> 4;
  const int t0 = c * CHUNK;
  const int tid = threadIdx.x;
  __shared__ float Ks[CHUNK][FDIM];  // 32 KB
  __shared__ float Vs[CHUNK][HD];    // 16 KB
  for (int i = tid; i < CHUNK * (FDIM / 4); i += 256) {
    const int r = i >> 5, c4 = (i & 31) << 2;
    *(float4*)&Ks[r][c4] = *(const float4*)&Kf[((size_t)bh * LSEQ + t0 + r) * FDIM + c4];
  }
  for (int i = tid; i < CHUNK * (HD / 4); i += 256) {
    const int r = i >> 4, c4 = (i & 15) << 2;
    *(float4*)&Vs[r][c4] = *(const float4*)&Vx[((size_t)bh * LSEQ + t0 + r) * HD + c4];
  }
  __syncthreads();
  float* Sb = &S[(size_t)blockIdx.x * FDIM * EV];
  for (int task = tid; task < 32 * 17; task += 256) {
    const int ft = task & 31;
    const int et = task >> 5;
    const int f0 = ft << 2;
    if (et == 16) {
      float s[4] = {};
      for (int t = 0; t < CHUNK; ++t) {
        const float4 k4 = *(const float4*)&Ks[t][f0];
        s[0] += k4.x; s[1] += k4.y; s[2] += k4.z; s[3] += k4.w;
      }
#pragma unroll
      for (int u = 0; u < 4; ++u) Sb[(f0 + u) * EV + 64] = s[u];
    } else {
      const int e0 = et << 2;
      float a[4][4] = {};
      for (int t = 0; t < CHUNK; ++t) {
        const float4 k4 = *(const float4*)&Ks[t][f0];
        const float4 v4 = *(const float4*)&Vs[t][e0];
        const float kv[4] = {k4.x, k4.y, k4.z, k4.w};
        const float vv[4] = {v4.x, v4.y, v4.z, v4.w};
#pragma unroll
        for (int i = 0; i < 4; ++i)
#pragma unroll
          for (int j = 0; j < 4; ++j)
            a[i][j] = fmaf(kv[i], vv[j], a[i][j]);
      }
#pragma unroll
      for (int i = 0; i < 4; ++i)
#pragma unroll
        for (int j = 0; j < 4; ++j)
          Sb[(f0 + i) * EV + e0 + j] = a[i][j];
    }
  }
}

// ---------------------------------------------------------------------------
// K3: in-place exclusive prefix scan over the NC chunk states per bh.
// ---------------------------------------------------------------------------
__global__ __launch_bounds__(256) void k_scan(float* __restrict__ S)
{
  const int bh = blockIdx.x >> 4;
  const int fg = blockIdx.x & 15;          // f-group of 8 rows
  float* Sb = S + (size_t)bh * NC * FDIM * EV + (size_t)fg * 8 * EV;
  const size_t cs = (size_t)FDIM * EV;
  for (int i = threadIdx.x; i < 8 * EV; i += 256) {
    float* p = Sb + i;
    float v[NC];
#pragma unroll
    for (int c = 0; c < NC; ++c) v[c] = p[c * cs];
    float s = 0.0f;
#pragma unroll
    for (int c = 0; c < NC; ++c) { const float t = v[c]; p[c * cs] = s; s += t; }
  }
}

// ---------------------------------------------------------------------------
// K4 v4: per-chunk output, all three matmuls on bf16 MFMA (fp32 accumulate).
//   Sc  = tril(Q @ K^T)              A=QL[t][f], B=KL[t][f]
//   num = Q @ P                      B=PT[e][f]  (P transposed, bf16)
//   PV  = Sc @ Vext                  A=ScL[m][t] (bf16 round-trip), B=VT[e][t]
// Denominator = 5th n-tile: PT col stack at e=64 + VT ones-row at e=64.
// n-tile-4 cols 65..79 read garbage LDS rows -> those D lanes are never used.
// ---------------------------------------------------------------------------
__global__ __launch_bounds__(256) void k_chunk_out(
    const float* __restrict__ Qf, const float* __restrict__ Kf,
    const float* __restrict__ Vx, const float* __restrict__ S,
    float* __restrict__ Out)
{
  const int c  = blockIdx.x & (NC - 1);
  const int bh = blockIdx.x >> 4;
  const int n  = bh >> 3, h = bh & 7;
  const int t0 = c * CHUNK;
  const int tid  = threadIdx.x;
  const int wave = tid >> 6, lane = tid & 63;
  const int quad = lane >> 4, lm = lane & 15;

  __shared__ short QL[64][128];    // [t][f] bf16  16384 B
  __shared__ short KL[64][128];    // [t][f] bf16  16384 B
  __shared__ short ScL[64][72];    // [m][t] bf16   9216 B (pad 8 -> 4-way max)
  __shared__ short PT[80][136];    // [e][f] bf16  21760 B (136: 16B-aligned rows)
  __shared__ short VT[80][72];     // [e][t] bf16  11520 B
  __shared__ float DenL[64];       //                256 B   total 75520 B

  // ---- stage Q,K chunks as bf16 [t][f] (coalesced 2KB/wave loads) ----
  const float* Qg = &Qf[((size_t)bh * LSEQ + t0) * FDIM];
  const float* Kg = &Kf[((size_t)bh * LSEQ + t0) * FDIM];
  {
    const int f8 = (tid & 15) << 3;
#pragma unroll
    for (int rr = 0; rr < 64; rr += 16) {
      const int r = rr + (tid >> 4);
      const float4 a0 = *(const float4*)&Qg[r * FDIM + f8];
      const float4 a1 = *(const float4*)&Qg[r * FDIM + f8 + 4];
      *(short8*)&QL[r][f8] = cvt8(a0, a1);
      const float4 b0 = *(const float4*)&Kg[r * FDIM + f8];
      const float4 b1 = *(const float4*)&Kg[r * FDIM + f8 + 4];
      *(short8*)&KL[r][f8] = cvt8(b0, b1);
    }
  }
  // ---- stage prefix state transposed: PT[e][f] = P[f][e] (bf16) ----
  {
    const float* Pg = &S[(size_t)(bh * NC + c) * FDIM * EV];
    for (int i = tid; i < FDIM * EV; i += 256) {
      const int f = i / EV, e = i - f * EV;
      PT[e][f] = (short)f2bf(Pg[i]);
    }
  }
  // ---- stage V transposed: VT[e][t] = V[t][e]; ones-row at e=64 ----
  {
    const float* Vg = &Vx[((size_t)bh * LSEQ + t0) * HD];
    for (int i = tid; i < CHUNK * (HD / 4); i += 256) {
      const int t = i >> 4, e4 = (i & 15) << 2;
      const float4 v4 = *(const float4*)&Vg[t * HD + e4];
      VT[e4 + 0][t] = (short)f2bf(v4.x);
      VT[e4 + 1][t] = (short)f2bf(v4.y);
      VT[e4 + 2][t] = (short)f2bf(v4.z);
      VT[e4 + 3][t] = (short)f2bf(v4.w);
    }
    if (tid < CHUNK) VT[64][tid] = (short)0x3F80;   // bf16 1.0
  }
  __syncthreads();

  // ---- A fragments from QL (wave's 16 rows) ----
  short8 aQ[4];
#pragma unroll
  for (int ks = 0; ks < 4; ++ks)
    aQ[ks] = *(const short8*)&QL[(wave << 4) + lm][(quad << 3) + (ks << 5)];

  // ---- phase 1: scores Sc = Q @ K^T, mask, round-trip bf16 ----
  floatx4 accS[4] = {};
#pragma unroll
  for (int nt = 0; nt < 4; ++nt)
#pragma unroll
    for (int ks = 0; ks < 4; ++ks) {
      const short8 b = *(const short8*)&KL[(nt << 4) + lm][(quad << 3) + (ks << 5)];
      accS[nt] = __builtin_amdgcn_mfma_f32_16x16x32_bf16(aQ[ks], b, accS[nt], 0, 0, 0);
    }
#pragma unroll
  for (int nt = 0; nt < 4; ++nt)
#pragma unroll
    for (int rg = 0; rg < 4; ++rg) {
      const int m = (wave << 4) + (quad << 2) + rg;
      const int t = (nt << 4) + lm;
      ScL[m][t] = (short)((t <= m) ? f2bf(accS[nt][rg]) : 0);
    }

  // ---- phase 2: num = Q @ P (+den col at n-tile 4) ----
  floatx4 accN[5] = {};
#pragma unroll
  for (int nt = 0; nt < 5; ++nt)
#pragma unroll
    for (int ks = 0; ks < 4; ++ks) {
      const short8 b = *(const short8*)&PT[(nt << 4) + lm][(quad << 3) + (ks << 5)];
      accN[nt] = __builtin_amdgcn_mfma_f32_16x16x32_bf16(aQ[ks], b, accN[nt], 0, 0, 0);
    }

  // ---- phase 3: PV = Sc @ Vext (+rowsum col at n-tile 4) ----
  // same-wave LDS write->read (ScL rows 16*wave..+15): no barrier needed
  short8 aS[2];
#pragma unroll
  for (int ks = 0; ks < 2; ++ks)
    aS[ks] = *(const short8*)&ScL[(wave << 4) + lm][(quad << 3) + (ks << 5)];
  floatx4 accV[5] = {};
#pragma unroll
  for (int nt = 0; nt < 5; ++nt)
#pragma unroll
    for (int ks = 0; ks < 2; ++ks) {
      const short8 b = *(const short8*)&VT[(nt << 4) + lm][(quad << 3) + (ks << 5)];
      accV[nt] = __builtin_amdgcn_mfma_f32_16x16x32_bf16(aS[ks], b, accV[nt], 0, 0, 0);
    }

  // ---- denominator broadcast via DenL (same-wave, no barrier) ----
  if (lm == 0) {
#pragma unroll
    for (int rg = 0; rg < 4; ++rg)
      DenL[(wave << 4) + (quad << 2) + rg] = accN[4][rg] + accV[4][rg];
  }

  // ---- epilogue: (num+PV)/den, store ----
#pragma unroll
  for (int rg = 0; rg < 4; ++rg) {
    const int m = (wave << 4) + (quad << 2) + rg;
    const float rden = 1.0f / DenL[m];
    const int l = t0 + m;
#pragma unroll
    for (int nt = 0; nt < 4; ++nt) {
      const float val = (accN[nt][rg] + accV[nt][rg]) * rden;
      Out[((size_t)(n * LSEQ + l)) * DD + h * HD + (nt << 4) + lm] = val;
    }
  }
}

// ---------------------------------------------------------------------------
extern "C" void kernel_launch(void* const* d_in, const int* in_sizes, int n_in,
                              void* d_out, int out_size, void* d_ws, size_t ws_size,
                              hipStream_t stream) {
  (void)in_sizes; (void)n_in; (void)out_size; (void)ws_size;
  const float* query  = (const float*)d_in[0];
  const float* keyseq = (const float*)d_in[1];
  const float* Wq     = (const float*)d_in[2];
  const float* Wk     = (const float*)d_in[3];
  const float* Wv     = (const float*)d_in[4];
  const float* pc     = (const float*)d_in[5];  // position_coeffs (H,d)
  const float* pw     = (const float*)d_in[6];  // position_weight (H,d,1)
  const float* pb     = (const float*)d_in[7];  // position_bias (H,d)
  float* out = (float*)d_out;

  float* ws = (float*)d_ws;
  float* Qf = ws;
  float* Kf = Qf + (size_t)NBH * LSEQ * FDIM;
  float* Vx = Kf + (size_t)NBH * LSEQ * FDIM;
  float* S  = Vx + (size_t)NBH * LSEQ * HD;
  // total ws: 29.5 MB

  k_proj      <<<768,      256, 0, stream>>>(query, keyseq, Wq, Wk, Wv, pw, pb, pc, Qf, Kf, Vx);
  k_chunk_sums<<<NBH * NC, 256, 0, stream>>>(Kf, Vx, S);
  k_scan      <<<NBH * NC, 256, 0, stream>>>(S);
  k_chunk_out <<<NBH * NC, 256, 0, stream>>>(Qf, Kf, Vx, S, out);
}

// Round 7
// 119.415 us; speedup vs baseline: 1.5435x; 1.0210x over previous
//
#include <hip/hip_runtime.h>
#include <cmath>

// Problem constants (from reference): N=2, Lq=Lk=1024, H=8, d=64, P=1, D=512
#define NB    2
#define LSEQ  1024
#define NH    8
#define HD    64
#define DD    512    // NH*HD
#define FDIM  128    // 2*HD  (cos|sin features)
#define EV    65     // HD + 1 (values + denominator unit column)
#define CHUNK 64
#define NC    16     // LSEQ / CHUNK
#define NBH   16     // NB*NH

typedef short short8 __attribute__((ext_vector_type(8)));   // 8 bf16 (4 VGPRs)
typedef float floatx4 __attribute__((ext_vector_type(4)));  // MFMA C/D frag

__device__ __forceinline__ float softplusf(float x) {
  return fmaxf(x, 0.0f) + log1pf(expf(-fabsf(x)));
}

__device__ __forceinline__ unsigned short f2bf(float f) {
  unsigned u = __float_as_uint(f);
  u += 0x7fffu + ((u >> 16) & 1u);
  return (unsigned short)(u >> 16);
}

__device__ __forceinline__ short8 cvt8(float4 a, float4 b) {
  short8 r;
  r[0] = (short)f2bf(a.x); r[1] = (short)f2bf(a.y);
  r[2] = (short)f2bf(a.z); r[3] = (short)f2bf(a.w);
  r[4] = (short)f2bf(b.x); r[5] = (short)f2bf(b.y);
  r[6] = (short)f2bf(b.z); r[7] = (short)f2bf(b.w);
  return r;
}

// ---------------------------------------------------------------------------
// K1 v2: ALL projections, bf16 MFMA, K-slice 64 (8 iters, half the barriers),
// register double-buffered global loads (issued right after barrier #2,
// consumed at next loop top -> latency hidden under LDS reads + MFMA).
// Blocks 0..255: q; 256..767: k/v.
// ---------------------------------------------------------------------------
__global__ __launch_bounds__(256) void k_proj(
    const float* __restrict__ Xq, const float* __restrict__ Xkv,
    const float* __restrict__ Wq, const float* __restrict__ Wk,
    const float* __restrict__ Wv, const float* __restrict__ pw,
    const float* __restrict__ pb, const float* __restrict__ pc,
    float* __restrict__ Qf, float* __restrict__ Kf, float* __restrict__ Vx)
{
  __shared__ short Al[64][72];   // [m][k] bf16, padded rows (9216 B)
  __shared__ short Bl[64][72];   // [e][k] bf16 (9216 B)
  const int b = blockIdx.x;
  int m0, e0, pmode;             // 0 = q, 1 = k, 2 = v
  const float *X, *W;
  if (b < 256) {
    m0 = (b >> 3) << 6; e0 = (b & 7) << 6;
    X = Xq; W = Wq + (size_t)e0 * DD; pmode = 0;
  } else {
    const int bb = b - 256;
    m0 = (bb >> 4) << 6;
    const int nt = bb & 15;
    e0 = (nt & 7) << 6;
    X = Xkv;
    if (nt < 8) { W = Wk + (size_t)e0 * DD; pmode = 1; }
    else        { W = Wv + (size_t)e0 * DD; pmode = 2; }
  }
  const int tid  = threadIdx.x;
  const int r    = tid >> 2;               // staging row 0..63
  const int ko   = (tid & 3) << 4;         // 0,16,32,48 shorts (16 per thread)
  const int wave = tid >> 6, lane = tid & 63;
  const int quad = lane >> 4, lm = lane & 15;
  const float* Ag = X + (size_t)(m0 + r) * DD + ko;
  const float* Bg = W + (size_t)r * DD + ko;
  float4 a[4], bb4[4];
#pragma unroll
  for (int u = 0; u < 4; ++u) {
    a[u]   = *(const float4*)(Ag + (u << 2));
    bb4[u] = *(const float4*)(Bg + (u << 2));
  }
  floatx4 acc[4] = {};
  for (int k0 = 0; k0 < DD; k0 += 64) {
    __syncthreads();
    *(short8*)&Al[r][ko]     = cvt8(a[0], a[1]);
    *(short8*)&Al[r][ko + 8] = cvt8(a[2], a[3]);
    *(short8*)&Bl[r][ko]     = cvt8(bb4[0], bb4[1]);
    *(short8*)&Bl[r][ko + 8] = cvt8(bb4[2], bb4[3]);
    __syncthreads();
    if (k0 + 64 < DD) {
#pragma unroll
      for (int u = 0; u < 4; ++u) {
        a[u]   = *(const float4*)(Ag + k0 + 64 + (u << 2));
        bb4[u] = *(const float4*)(Bg + k0 + 64 + (u << 2));
      }
    }
#pragma unroll
    for (int ks = 0; ks < 2; ++ks) {
      const short8 af = *(const short8*)&Al[(wave << 4) + lm][(quad << 3) + (ks << 5)];
#pragma unroll
      for (int t = 0; t < 4; ++t) {
        const short8 bf = *(const short8*)&Bl[(t << 4) + lm][(quad << 3) + (ks << 5)];
        acc[t] = __builtin_amdgcn_mfma_f32_16x16x32_bf16(af, bf, acc[t], 0, 0, 0);
      }
    }
  }
#pragma unroll
  for (int t = 0; t < 4; ++t) {
    const int e = e0 + (t << 4) + lm;
    const int h = e >> 6, jj = e & 63;
    if (pmode == 2) {
#pragma unroll
      for (int rg = 0; rg < 4; ++rg) {
        const int m = m0 + (wave << 4) + (quad << 2) + rg;
        const int n = m >> 10, l = m & 1023;
        Vx[((size_t)(n * NH + h) * LSEQ + l) * HD + jj] = acc[t][rg];
      }
    } else {
      const float pwv = pw[e];
      const float pbv = (pmode == 0) ? pb[e] : 0.0f;
      const float pcv = (pmode == 0) ? pc[e] : 1.0f;
      float* base = (pmode == 0) ? Qf : Kf;
#pragma unroll
      for (int rg = 0; rg < 4; ++rg) {
        const int m = m0 + (wave << 4) + (quad << 2) + rg;
        const int n = m >> 10, l = m & 1023;
        const float v = softplusf(acc[t][rg]) * pcv;
        const float ang = fmaf((float)l, pwv, pbv);
        const float sn = __sinf(ang), cs = __cosf(ang);
        float* dst = &base[((size_t)(n * NH + h) * LSEQ + l) * FDIM + jj];
        dst[0]  = v * cs;
        dst[64] = v * sn;
      }
    }
  }
}

// ---------------------------------------------------------------------------
// K2 v2: per-chunk state sums on bf16 MFMA.
// S[f][e] = sum_t K[t][f]*Vext[t][e]:  A = K^T [f][t], B = V^T [e][t],
// ones-row at e=64 -> denominator column via 5th e-tile (cols 65..79 unused).
// Grid 512: blk = bh*32 + c*2 + fh  (fh = f-half of 64 rows) -> 2 blocks/CU.
// ---------------------------------------------------------------------------
__global__ __launch_bounds__(256) void k_chunk_sums(
    const float* __restrict__ Kf, const float* __restrict__ Vx,
    float* __restrict__ S)
{
  const int blk = blockIdx.x;
  const int bh  = blk >> 5;
  const int c   = (blk >> 1) & (NC - 1);
  const int fh  = blk & 1;
  const int f0  = fh << 6;
  const int t0  = c * CHUNK;
  const int tid  = threadIdx.x;
  const int wave = tid >> 6, lane = tid & 63;
  const int quad = lane >> 4, lm = lane & 15;

  __shared__ short KT[64][72];   // [f-f0][t] bf16  9216 B
  __shared__ short VT[80][72];   // [e][t]    bf16 11520 B

  // stage K^T (this f-half): lanes sweep t -> 2-way-max bank aliasing
  for (int i = tid; i < 64 * 16; i += 256) {
    const int t = i & 63, f4 = (i >> 6) << 2;
    const float4 k4 = *(const float4*)&Kf[((size_t)bh * LSEQ + t0 + t) * FDIM + f0 + f4];
    KT[f4 + 0][t] = (short)f2bf(k4.x);
    KT[f4 + 1][t] = (short)f2bf(k4.y);
    KT[f4 + 2][t] = (short)f2bf(k4.z);
    KT[f4 + 3][t] = (short)f2bf(k4.w);
  }
  // stage V^T + ones row at e=64
  for (int i = tid; i < 64 * 16; i += 256) {
    const int t = i & 63, e4 = (i >> 6) << 2;
    const float4 v4 = *(const float4*)&Vx[((size_t)bh * LSEQ + t0 + t) * HD + e4];
    VT[e4 + 0][t] = (short)f2bf(v4.x);
    VT[e4 + 1][t] = (short)f2bf(v4.y);
    VT[e4 + 2][t] = (short)f2bf(v4.z);
    VT[e4 + 3][t] = (short)f2bf(v4.w);
  }
  if (tid < CHUNK) VT[64][tid] = (short)0x3F80;   // bf16 1.0
  __syncthreads();

  // wave w -> f-tile w (16 f rows); e-tiles 0..4; K=64 = 2 MFMA k-steps
  short8 aK[2];
#pragma unroll
  for (int ks = 0; ks < 2; ++ks)
    aK[ks] = *(const short8*)&KT[(wave << 4) + lm][(quad << 3) + (ks << 5)];
  floatx4 acc[5] = {};
#pragma unroll
  for (int nt = 0; nt < 5; ++nt)
#pragma unroll
    for (int ks = 0; ks < 2; ++ks) {
      const short8 bf = *(const short8*)&VT[(nt << 4) + lm][(quad << 3) + (ks << 5)];
      acc[nt] = __builtin_amdgcn_mfma_f32_16x16x32_bf16(aK[ks], bf, acc[nt], 0, 0, 0);
    }

  float* Sb = &S[(size_t)(bh * NC + c) * FDIM * EV];
#pragma unroll
  for (int nt = 0; nt < 4; ++nt)
#pragma unroll
    for (int rg = 0; rg < 4; ++rg) {
      const int f = f0 + (wave << 4) + (quad << 2) + rg;
      Sb[f * EV + (nt << 4) + lm] = acc[nt][rg];
    }
  if (lm == 0) {
#pragma unroll
    for (int rg = 0; rg < 4; ++rg) {
      const int f = f0 + (wave << 4) + (quad << 2) + rg;
      Sb[f * EV + 64] = acc[4][rg];
    }
  }
}

// ---------------------------------------------------------------------------
// K3: in-place exclusive prefix scan over the NC chunk states per bh.
// ---------------------------------------------------------------------------
__global__ __launch_bounds__(256) void k_scan(float* __restrict__ S)
{
  const int bh = blockIdx.x >> 4;
  const int fg = blockIdx.x & 15;          // f-group of 8 rows
  float* Sb = S + (size_t)bh * NC * FDIM * EV + (size_t)fg * 8 * EV;
  const size_t cs = (size_t)FDIM * EV;
  for (int i = threadIdx.x; i < 8 * EV; i += 256) {
    float* p = Sb + i;
    float v[NC];
#pragma unroll
    for (int c = 0; c < NC; ++c) v[c] = p[c * cs];
    float s = 0.0f;
#pragma unroll
    for (int c = 0; c < NC; ++c) { const float t = v[c]; p[c * cs] = s; s += t; }
  }
}

// ---------------------------------------------------------------------------
// K4 v4: per-chunk output, all three matmuls on bf16 MFMA (fp32 accumulate).
// ---------------------------------------------------------------------------
__global__ __launch_bounds__(256) void k_chunk_out(
    const float* __restrict__ Qf, const float* __restrict__ Kf,
    const float* __restrict__ Vx, const float* __restrict__ S,
    float* __restrict__ Out)
{
  const int c  = blockIdx.x & (NC - 1);
  const int bh = blockIdx.x >> 4;
  const int n  = bh >> 3, h = bh & 7;
  const int t0 = c * CHUNK;
  const int tid  = threadIdx.x;
  const int wave = tid >> 6, lane = tid & 63;
  const int quad = lane >> 4, lm = lane & 15;

  __shared__ short QL[64][128];    // [t][f] bf16  16384 B
  __shared__ short KL[64][128];    // [t][f] bf16  16384 B
  __shared__ short ScL[64][72];    // [m][t] bf16   9216 B
  __shared__ short PT[80][136];    // [e][f] bf16  21760 B
  __shared__ short VT[80][72];     // [e][t] bf16  11520 B
  __shared__ float DenL[64];       //                256 B

  const float* Qg = &Qf[((size_t)bh * LSEQ + t0) * FDIM];
  const float* Kg = &Kf[((size_t)bh * LSEQ + t0) * FDIM];
  {
    const int f8 = (tid & 15) << 3;
#pragma unroll
    for (int rr = 0; rr < 64; rr += 16) {
      const int r = rr + (tid >> 4);
      const float4 a0 = *(const float4*)&Qg[r * FDIM + f8];
      const float4 a1 = *(const float4*)&Qg[r * FDIM + f8 + 4];
      *(short8*)&QL[r][f8] = cvt8(a0, a1);
      const float4 b0 = *(const float4*)&Kg[r * FDIM + f8];
      const float4 b1 = *(const float4*)&Kg[r * FDIM + f8 + 4];
      *(short8*)&KL[r][f8] = cvt8(b0, b1);
    }
  }
  {
    const float* Pg = &S[(size_t)(bh * NC + c) * FDIM * EV];
    for (int i = tid; i < FDIM * EV; i += 256) {
      const int f = i / EV, e = i - f * EV;
      PT[e][f] = (short)f2bf(Pg[i]);
    }
  }
  {
    const float* Vg = &Vx[((size_t)bh * LSEQ + t0) * HD];
    for (int i = tid; i < CHUNK * (HD / 4); i += 256) {
      const int t = i >> 4, e4 = (i & 15) << 2;
      const float4 v4 = *(const float4*)&Vg[t * HD + e4];
      VT[e4 + 0][t] = (short)f2bf(v4.x);
      VT[e4 + 1][t] = (short)f2bf(v4.y);
      VT[e4 + 2][t] = (short)f2bf(v4.z);
      VT[e4 + 3][t] = (short)f2bf(v4.w);
    }
    if (tid < CHUNK) VT[64][tid] = (short)0x3F80;   // bf16 1.0
  }
  __syncthreads();

  short8 aQ[4];
#pragma unroll
  for (int ks = 0; ks < 4; ++ks)
    aQ[ks] = *(const short8*)&QL[(wave << 4) + lm][(quad << 3) + (ks << 5)];

  // phase 1: scores
  floatx4 accS[4] = {};
#pragma unroll
  for (int nt = 0; nt < 4; ++nt)
#pragma unroll
    for (int ks = 0; ks < 4; ++ks) {
      const short8 b = *(const short8*)&KL[(nt << 4) + lm][(quad << 3) + (ks << 5)];
      accS[nt] = __builtin_amdgcn_mfma_f32_16x16x32_bf16(aQ[ks], b, accS[nt], 0, 0, 0);
    }
#pragma unroll
  for (int nt = 0; nt < 4; ++nt)
#pragma unroll
    for (int rg = 0; rg < 4; ++rg) {
      const int m = (wave << 4) + (quad << 2) + rg;
      const int t = (nt << 4) + lm;
      ScL[m][t] = (short)((t <= m) ? f2bf(accS[nt][rg]) : 0);
    }

  // phase 2: num = Q @ P (+den col)
  floatx4 accN[5] = {};
#pragma unroll
  for (int nt = 0; nt < 5; ++nt)
#pragma unroll
    for (int ks = 0; ks < 4; ++ks) {
      const short8 b = *(const short8*)&PT[(nt << 4) + lm][(quad << 3) + (ks << 5)];
      accN[nt] = __builtin_amdgcn_mfma_f32_16x16x32_bf16(aQ[ks], b, accN[nt], 0, 0, 0);
    }

  // phase 3: PV = Sc @ Vext (+rowsum col); same-wave ScL access, no barrier
  short8 aS[2];
#pragma unroll
  for (int ks = 0; ks < 2; ++ks)
    aS[ks] = *(const short8*)&ScL[(wave << 4) + lm][(quad << 3) + (ks << 5)];
  floatx4 accV[5] = {};
#pragma unroll
  for (int nt = 0; nt < 5; ++nt)
#pragma unroll
    for (int ks = 0; ks < 2; ++ks) {
      const short8 b = *(const short8*)&VT[(nt << 4) + lm][(quad << 3) + (ks << 5)];
      accV[nt] = __builtin_amdgcn_mfma_f32_16x16x32_bf16(aS[ks], b, accV[nt], 0, 0, 0);
    }

  if (lm == 0) {
#pragma unroll
    for (int rg = 0; rg < 4; ++rg)
      DenL[(wave << 4) + (quad << 2) + rg] = accN[4][rg] + accV[4][rg];
  }

#pragma unroll
  for (int rg = 0; rg < 4; ++rg) {
    const int m = (wave << 4) + (quad << 2) + rg;
    const float rden = 1.0f / DenL[m];
    const int l = t0 + m;
#pragma unroll
    for (int nt = 0; nt < 4; ++nt) {
      const float val = (accN[nt][rg] + accV[nt][rg]) * rden;
      Out[((size_t)(n * LSEQ + l)) * DD + h * HD + (nt << 4) + lm] = val;
    }
  }
}

// ---------------------------------------------------------------------------
extern "C" void kernel_launch(void* const* d_in, const int* in_sizes, int n_in,
                              void* d_out, int out_size, void* d_ws, size_t ws_size,
                              hipStream_t stream) {
  (void)in_sizes; (void)n_in; (void)out_size; (void)ws_size;
  const float* query  = (const float*)d_in[0];
  const float* keyseq = (const float*)d_in[1];
  const float* Wq     = (const float*)d_in[2];
  const float* Wk     = (const float*)d_in[3];
  const float* Wv     = (const float*)d_in[4];
  const float* pc     = (const float*)d_in[5];  // position_coeffs (H,d)
  const float* pw     = (const float*)d_in[6];  // position_weight (H,d,1)
  const float* pb     = (const float*)d_in[7];  // position_bias (H,d)
  float* out = (float*)d_out;

  float* ws = (float*)d_ws;
  float* Qf = ws;
  float* Kf = Qf + (size_t)NBH * LSEQ * FDIM;
  float* Vx = Kf + (size_t)NBH * LSEQ * FDIM;
  float* S  = Vx + (size_t)NBH * LSEQ * HD;
  // total ws: 29.5 MB

  k_proj      <<<768,          256, 0, stream>>>(query, keyseq, Wq, Wk, Wv, pw, pb, pc, Qf, Kf, Vx);
  k_chunk_sums<<<NBH * NC * 2, 256, 0, stream>>>(Kf, Vx, S);
  k_scan      <<<NBH * NC,     256, 0, stream>>>(S);
  k_chunk_out <<<NBH * NC,     256, 0, stream>>>(Qf, Kf, Vx, S, out);
}